// Round 5
// baseline (428.113 us; speedup 1.0000x reference)
//
#include <hip/hip_runtime.h>
#include <hip/hip_bf16.h>
#include <cstdint>
#include <cmath>

// ---------------- types / helpers ----------------
typedef int intx4 __attribute__((ext_vector_type(4)));

#define EPSQ 1e-5f

// async global->LDS, 16B per lane. LDS dest = wave-uniform base + lane*16.
__device__ __forceinline__ void async16(const void* g, void* l) {
  __builtin_amdgcn_global_load_lds(
      (const __attribute__((address_space(1))) unsigned int*)(uintptr_t)g,
      (__attribute__((address_space(3))) unsigned int*)(unsigned int)(uintptr_t)l,
      16, 0, 0);
}

__device__ __forceinline__ int q8(float v, float scale, float lo, float hi) {
  return (int)fminf(fmaxf(rintf(v * scale), lo), hi);
}

// packed snorm16 quant: D = {rne(clamp(a,-1,1)*32767), rne(clamp(b,-1,1)*32767)}
// Single VOP instr; replaces mul+rint+min+max+cvt per element.
__device__ __forceinline__ unsigned int pknorm_i16(float a, float b) {
  unsigned int r;
  asm("v_cvt_pknorm_i16_f32 %0, %1, %2" : "=v"(r) : "v"(a), "v"(b));
  return r;
}

// Branchless exact-GELU via Abramowitz-Stegun 7.1.26 rational erf.
__device__ __forceinline__ float fast_gelu(float y) {
  const float t = y * 0.70710678118654752f;
  const float x = fabsf(t);
  const float u = __builtin_amdgcn_rcpf(__builtin_fmaf(0.3275911f, x, 1.0f));
  float p = __builtin_fmaf(1.061405429f, u, -1.453152027f);
  p = __builtin_fmaf(p, u, 1.421413741f);
  p = __builtin_fmaf(p, u, -0.284496736f);
  p = __builtin_fmaf(p, u, 0.254829592f);
  p = p * u;
  const float e = __expf(-x * x);
  const float erf_abs = __builtin_fmaf(-p, e, 1.0f);
  const float erf_t = copysignf(erf_abs, t);
  return 0.5f * y * (1.0f + erf_t);
}

// ---------------- init ----------------
__global__ void k_init(float* rowmax, double* sums) {
  int i = blockIdx.x * 256 + threadIdx.x;
  if (i < 16384) rowmax[i] = 0.0f;
  if (i < 2) sums[i] = 0.0;
}

// ---------------- abs-sum of 2x 4194304 fp32 (-> fp64 acc), both weights ----------
__global__ __launch_bounds__(256) void k_absmean2(const float* __restrict__ W1,
                                                  const float* __restrict__ W2,
                                                  double* __restrict__ sums) {
  __shared__ double wsum[4];
  const int tid = threadIdx.x;
  const int which = blockIdx.x >> 11;                 // 0: W1, 1: W2
  const float* __restrict__ W = which ? W2 : W1;
  const size_t base = ((size_t)(blockIdx.x & 2047) * 256 + tid) * 8;
  float4 a = *(const float4*)(W + base);
  float4 b = *(const float4*)(W + base + 4);
  float s = fabsf(a.x) + fabsf(a.y) + fabsf(a.z) + fabsf(a.w) +
            fabsf(b.x) + fabsf(b.y) + fabsf(b.z) + fabsf(b.w);
  double d = (double)s;
#pragma unroll
  for (int i = 1; i < 64; i <<= 1) d += __shfl_xor(d, i);
  const int lane = tid & 63, wave = tid >> 6;
  if (lane == 0) wsum[wave] = d;
  __syncthreads();
  if (tid == 0) atomicAdd(sums + which, wsum[0] + wsum[1] + wsum[2] + wsum[3]);
}

// ---------------- ternary weight quant (fp32 in) -> int8 {-1,0,1}, both weights ----
__global__ __launch_bounds__(256) void k_quantw2(const float* __restrict__ W1,
                                                 const float* __restrict__ W2,
                                                 signed char* __restrict__ W1Q,
                                                 signed char* __restrict__ W2Q,
                                                 const double* __restrict__ sums) {
  const int which = blockIdx.x >> 11;
  const float* __restrict__ W = which ? W2 : W1;
  signed char* __restrict__ WQ = which ? W2Q : W1Q;
  const float s = fmaxf((float)(sums[which] * (1.0 / 4194304.0)), EPSQ);
  const float inv_s = 1.0f / s;
  const size_t base = ((size_t)(blockIdx.x & 2047) * 256 + threadIdx.x) * 8;
  float4 a = *(const float4*)(W + base);
  float4 b = *(const float4*)(W + base + 4);
  float v[8] = {a.x, a.y, a.z, a.w, b.x, b.y, b.z, b.w};
  unsigned int lo = 0, hi = 0;
#pragma unroll
  for (int j = 0; j < 4; ++j) {
    lo |= ((unsigned int)(q8(v[j], inv_s, -1.f, 1.f) & 0xff)) << (8 * j);
    hi |= ((unsigned int)(q8(v[4 + j], inv_s, -1.f, 1.f) & 0xff)) << (8 * j);
  }
  uint2 o; o.x = lo; o.y = hi;
  *(uint2*)(WQ + base) = o;
}

// ---------------- per-token int8 act quant of x (fp32 in, 1024/row) ----------------
__global__ __launch_bounds__(256) void k_quantx(const float* __restrict__ X,
                                                signed char* __restrict__ XQ,
                                                float* __restrict__ dqx) {
  __shared__ float wmax[4];
  const int row = blockIdx.x, tid = threadIdx.x;
  const size_t base = (size_t)row * 1024 + tid * 4;
  float4 a = *(const float4*)(X + base);
  float m = fmaxf(fmaxf(fabsf(a.x), fabsf(a.y)), fmaxf(fabsf(a.z), fabsf(a.w)));
#pragma unroll
  for (int i = 1; i < 64; i <<= 1) m = fmaxf(m, __shfl_xor(m, i));
  const int lane = tid & 63, wave = tid >> 6;
  if (lane == 0) wmax[wave] = m;
  __syncthreads();
  m = fmaxf(fmaxf(wmax[0], wmax[1]), fmaxf(wmax[2], wmax[3]));
  m = fmaxf(m, EPSQ);
  const float scale = 127.f / m;
  if (tid == 0) dqx[row] = m * (1.f / 127.f);
  unsigned int p = ((unsigned int)(q8(a.x, scale, -128.f, 127.f) & 0xff)) |
                   ((unsigned int)(q8(a.y, scale, -128.f, 127.f) & 0xff) << 8) |
                   ((unsigned int)(q8(a.z, scale, -128.f, 127.f) & 0xff) << 16) |
                   ((unsigned int)(q8(a.w, scale, -128.f, 127.f) & 0xff) << 24);
  *(unsigned int*)(XQ + base) = p;
}

// ---------------- 128x128 2-slot counted-vmcnt GEMM mainloop -----------------------
// C[128x128] = A[128xK] * B[128xK]^T, int8 -> int32 exact (mfma_i32_16x16x64_i8).
// 256 threads = 4 waves (2x2); per-wave 64x64 = 4x4 frags. K-tile = 64 B.
// LDS: 2 slots x (A 8KB + B 8KB) = 32 KB -> with ~150 regs/wave and
// __launch_bounds__(256,3): 3 blocks/CU co-resident. One block's epilogue VALU
// overlaps other blocks' mainloop MFMA (the combination R3/R4 each lacked).
// Counted pipeline (T3/T4): steady state waits vmcnt(4) (next tile's 4 loads
// stay in flight across raw s_barrier); never drains to 0 until the tail.
// Ledger: iter t: issue tile t+1 into slot (t+1)&1 (holds tile t-1, whose reads
// finished before iter t-1's trailing barrier); vmcnt(4) retires tile t's 4
// loads; leading barrier -> all waves' tile-t data visible; ds_read+MFMA
// (compiler lgkmcnt orders reads before MFMA, MFMA before trailing barrier);
// trailing barrier -> slot reusable.
// Swizzle: phys granule16 = logical ^ ((row>>1)&3) on BOTH the global source
// and the ds_read offset -> 2-way max b128 conflict (free); R4 measured 0.
template <int KB>
__device__ __forceinline__ void gemm_mainloop(const signed char* __restrict__ A,
                                              const signed char* __restrict__ B,
                                              int bm, int bn, int tid, char* lds,
                                              intx4 (&acc)[4][4]) {
  const int wave = tid >> 6, lane = tid & 63;
  const int wm = wave >> 1, wn = wave & 1;
  const int kq = lane >> 4, lc = lane & 15;
  constexpr int NT = KB / 64;

  size_t goff[4];  // rounds 0-1: A, rounds 2-3: B
  int lbase[4];    // wave-uniform LDS dest base (HW adds lane*16)
#pragma unroll
  for (int i = 0; i < 4; ++i) {
    const int idx = (i & 1) * 256 + tid;   // 0..511 within the matrix
    const int r = idx >> 2, g = idx & 3;
    const int gl = g ^ ((r >> 1) & 3);     // pre-swizzled global granule
    const int rowbase = ((i < 2) ? bm : bn) * 128 + r;
    goff[i] = (size_t)rowbase * KB + gl * 16;
    lbase[i] = ((i >= 2) ? 8192 : 0) + (i & 1) * 4096 + wave * 1024;
  }

  int aoff[4], boff[4];  // fragment ds_read offsets within a slot
#pragma unroll
  for (int t = 0; t < 4; ++t) {
    const int ra = wm * 64 + t * 16 + lc;
    aoff[t] = ra * 64 + ((kq ^ ((ra >> 1) & 3)) << 4);
    const int rb = wn * 64 + t * 16 + lc;
    boff[t] = 8192 + rb * 64 + ((kq ^ ((rb >> 1) & 3)) << 4);
  }

#pragma unroll
  for (int ti = 0; ti < 4; ++ti)
#pragma unroll
    for (int tj = 0; tj < 4; ++tj) {
      intx4 z = {0, 0, 0, 0};
      acc[ti][tj] = z;
    }

  // prologue: stage tile 0 into slot 0
#pragma unroll
  for (int i = 0; i < 4; ++i)
    async16(((i < 2) ? A : B) + goff[i], lds + lbase[i]);

  for (int t = 0; t < NT; ++t) {
    if (t + 1 < NT) {
      char* nslot = lds + ((t + 1) & 1) * 16384;
      const size_t k0 = (size_t)(t + 1) * 64;
#pragma unroll
      for (int i = 0; i < 4; ++i)
        async16(((i < 2) ? A : B) + goff[i] + k0, nslot + lbase[i]);
      asm volatile("s_waitcnt vmcnt(4)" ::: "memory");
    } else {
      asm volatile("s_waitcnt vmcnt(0)" ::: "memory");
    }
    __builtin_amdgcn_s_barrier();
    __builtin_amdgcn_sched_barrier(0);

    char* slot = lds + (t & 1) * 16384;
    intx4 af[4], bfr[4];
#pragma unroll
    for (int i = 0; i < 4; ++i) af[i] = *(const intx4*)(slot + aoff[i]);
#pragma unroll
    for (int i = 0; i < 4; ++i) bfr[i] = *(const intx4*)(slot + boff[i]);
    __builtin_amdgcn_s_setprio(1);
#pragma unroll
    for (int ti = 0; ti < 4; ++ti)
#pragma unroll
      for (int tj = 0; tj < 4; ++tj)
        acc[ti][tj] =
            __builtin_amdgcn_mfma_i32_16x16x64_i8(af[ti], bfr[tj], acc[ti][tj], 0, 0, 0);
    __builtin_amdgcn_s_setprio(0);
    __builtin_amdgcn_sched_barrier(0);
    __builtin_amdgcn_s_barrier();
  }
}

// ---------------- GEMM1 + dequant + exact GELU + packed int16 h store --------------
// h stored quad-row-packed: cell (qr, col) = 4 consecutive rows' int16 values as
// one uint2 (v_cvt_pknorm_i16_f32: rne+clamp+x32767 in 1 instr / 2 elems).
// Replaces 128 scalar short-stores + ~900 VALU with 32 uint2 stores + ~300 VALU.
__global__ __launch_bounds__(256, 3) void k_gemm1(const signed char* __restrict__ A,
                                                  const signed char* __restrict__ B,
                                                  const float* __restrict__ dqx,
                                                  const double* __restrict__ sums,
                                                  short* __restrict__ HSP,
                                                  float* __restrict__ mblk,
                                                  float* __restrict__ rowmax) {
  __shared__ __attribute__((aligned(16))) char lds[32768];
  __shared__ float smax[128];
  const int tid = threadIdx.x;
  const int bm = blockIdx.x, bn = blockIdx.y;

  intx4 acc[4][4];
  gemm_mainloop<1024>(A, B, bm, bn, tid, lds, acc);

  const int wave = tid >> 6, lane = tid & 63;
  const int wm = wave >> 1, wn = wave & 1;
  const int kq = lane >> 4, lc = lane & 15;
  const float s1 = fmaxf((float)(sums[0] * (1.0 / 4194304.0)), EPSQ);

  if (tid < 128) smax[tid] = 0.0f;
  __syncthreads();

  // pass 1: dequant + GELU, stash h bits into acc; per-row block max via
  // 16-lane shuffle reduce (lanes sharing kq share rows), one atomic per group.
#pragma unroll
  for (int ti = 0; ti < 4; ++ti) {
#pragma unroll
    for (int r = 0; r < 4; ++r) {
      const int lrow = wm * 64 + ti * 16 + kq * 4 + r;
      const int crow = bm * 128 + lrow;  // chunk-local row
      const float f = s1 * dqx[crow];
      float mx = 0.f;
#pragma unroll
      for (int tj = 0; tj < 4; ++tj) {
        float y = (float)acc[ti][tj][r] * f;
        float h = fast_gelu(y);
        acc[ti][tj][r] = (int)__float_as_uint(h);
        mx = fmaxf(mx, fabsf(h));
      }
#pragma unroll
      for (int s = 1; s < 16; s <<= 1) mx = fmaxf(mx, __shfl_xor(mx, s));
      if (lc == 0) atomicMax((unsigned int*)&smax[lrow], __float_as_uint(mx));
    }
  }
  __syncthreads();
  if (tid < 128) {
    mblk[(size_t)(bm * 128 + tid) * 32 + bn] = smax[tid];
    atomicMax((unsigned int*)&rowmax[bm * 128 + tid], __float_as_uint(smax[tid]));
  }

  // pass 2: packed snorm16 quad-row store. acc[ti][tj][0..3] = 4 consecutive
  // rows, same column -> 2x pknorm + 1 uint2 store per cell.
#pragma unroll
  for (int ti = 0; ti < 4; ++ti) {
    const int lrow0 = wm * 64 + ti * 16 + kq * 4;
    const int qr = (bm * 128 + lrow0) >> 2;  // chunk-local quad-row
    float inv[4];
#pragma unroll
    for (int r = 0; r < 4; ++r)
      inv[r] = __builtin_amdgcn_rcpf(fmaxf(smax[lrow0 + r], 1e-30f));
#pragma unroll
    for (int tj = 0; tj < 4; ++tj) {
      const int gcol = bn * 128 + wn * 64 + tj * 16 + lc;
      const float h0 = __uint_as_float((unsigned int)acc[ti][tj][0]) * inv[0];
      const float h1 = __uint_as_float((unsigned int)acc[ti][tj][1]) * inv[1];
      const float h2 = __uint_as_float((unsigned int)acc[ti][tj][2]) * inv[2];
      const float h3 = __uint_as_float((unsigned int)acc[ti][tj][3]) * inv[3];
      uint2 o;
      o.x = pknorm_i16(h0, h1);
      o.y = pknorm_i16(h2, h3);
      *(uint2*)(HSP + ((size_t)qr * 4096 + gcol) * 4) = o;
    }
  }
}

// ---------------- requantize h: packed int16 (block scale) -> int8 (row scale) -----
// Consumes the quad-row-permuted HSP layout, emits canonical HQ [rows][4096] i8.
// BW-bound (192 MB); the layout shuffle is free here.
__global__ __launch_bounds__(256) void k_quanth(const short* __restrict__ HSP,
                                                const float* __restrict__ mblk,
                                                const float* __restrict__ rowmax,
                                                signed char* __restrict__ HQ) {
  const int gid = blockIdx.x * 256 + threadIdx.x;
  const int qr = gid >> 8;            // chunk-local quad-row (== blockIdx.x)
  const int cg = gid & 255;           // 16-col group
  const int c0 = cg * 16;
  const int blk = c0 >> 7;            // 128-col block (same for all 16 cols)
  const int row0 = qr * 4;            // chunk-local row
  float fb[4];
#pragma unroll
  for (int r = 0; r < 4; ++r) {
    const float m = fmaxf(rowmax[row0 + r], EPSQ);
    fb[r] = mblk[(size_t)(row0 + r) * 32 + blk] * (127.0f / 32767.0f) / m;
  }
  const uint4* src = (const uint4*)(HSP + ((size_t)qr * 4096 + c0) * 4);
  uint4 L[8];
#pragma unroll
  for (int j = 0; j < 8; ++j) L[j] = src[j];

  unsigned int out[4][4] = {};
#pragma unroll
  for (int j = 0; j < 16; ++j) {
    const unsigned int u01 = (j & 1) ? L[j >> 1].z : L[j >> 1].x;
    const unsigned int u23 = (j & 1) ? L[j >> 1].w : L[j >> 1].y;
    const float s0 = (float)(short)(u01 & 0xffff);
    const float s1 = (float)(short)(u01 >> 16);
    const float s2 = (float)(short)(u23 & 0xffff);
    const float s3 = (float)(short)(u23 >> 16);
    out[0][j >> 2] |= ((unsigned int)(q8(s0, fb[0], -128.f, 127.f) & 0xff)) << (8 * (j & 3));
    out[1][j >> 2] |= ((unsigned int)(q8(s1, fb[1], -128.f, 127.f) & 0xff)) << (8 * (j & 3));
    out[2][j >> 2] |= ((unsigned int)(q8(s2, fb[2], -128.f, 127.f) & 0xff)) << (8 * (j & 3));
    out[3][j >> 2] |= ((unsigned int)(q8(s3, fb[3], -128.f, 127.f) & 0xff)) << (8 * (j & 3));
  }
#pragma unroll
  for (int r = 0; r < 4; ++r) {
    uint4 o; o.x = out[r][0]; o.y = out[r][1]; o.z = out[r][2]; o.w = out[r][3];
    *(uint4*)(HQ + (size_t)(row0 + r) * 4096 + c0) = o;
  }
}

// ---------------- GEMM2 + dequant -> fp32 out (global rows, single launch) ----------
__global__ __launch_bounds__(256, 3) void k_gemm2(const signed char* __restrict__ A,
                                                  const signed char* __restrict__ B,
                                                  const float* __restrict__ rowmax,
                                                  const double* __restrict__ sums,
                                                  float* __restrict__ OUT) {
  __shared__ __attribute__((aligned(16))) char lds[32768];
  const int tid = threadIdx.x;
  const int bm = blockIdx.x, bn = blockIdx.y;

  intx4 acc[4][4];
  gemm_mainloop<4096>(A, B, bm, bn, tid, lds, acc);

  const int wave = tid >> 6, lane = tid & 63;
  const int wm = wave >> 1, wn = wave & 1;
  const int kq = lane >> 4, lc = lane & 15;
  const float s2 = fmaxf((float)(sums[0] * (1.0 / 4194304.0)), EPSQ);
#pragma unroll
  for (int ti = 0; ti < 4; ++ti) {
#pragma unroll
    for (int r = 0; r < 4; ++r) {
      const int crow = bm * 128 + wm * 64 + ti * 16 + kq * 4 + r;
      const float dqh = fmaxf(rowmax[crow], EPSQ) * (1.f / 127.f);
      const float f = s2 * dqh;
#pragma unroll
      for (int tj = 0; tj < 4; ++tj) {
        const int gcol = bn * 128 + wn * 64 + tj * 16 + lc;
        OUT[(size_t)crow * 1024 + gcol] = (float)acc[ti][tj][r] * f;
      }
    }
  }
}

// ---------------- launcher ----------------
extern "C" void kernel_launch(void* const* d_in, const int* in_sizes, int n_in,
                              void* d_out, int out_size, void* d_ws, size_t ws_size,
                              hipStream_t stream) {
  const float* X  = (const float*)d_in[0];  // [16384][1024] fp32
  const float* W1 = (const float*)d_in[1];  // [4096][1024]  fp32
  const float* W2 = (const float*)d_in[2];  // [1024][4096]  fp32
  float* OUT = (float*)d_out;               // [16384][1024] fp32 (64 MB)

  char* ws = (char*)d_ws;
  // Fixed-footprint region: 11 MB misc + 64 MB full HQ = 75 MB
  signed char* W1Q = (signed char*)(ws);                            // 4 MB
  signed char* W2Q = (signed char*)(ws + (4u << 20));               // 4 MB
  float* DQX       = (float*)(ws + (8u << 20));                     // 64 KB
  float* ROWMAX    = (float*)(ws + (8u << 20) + 65536);             // 64 KB
  double* SUMS     = (double*)(ws + (8u << 20) + 131072);           // 16 B
  float* MBLK      = (float*)(ws + (9u << 20));                     // 2 MB [16384][32]
  signed char* HQ  = (signed char*)(ws + (11u << 20));              // 64 MB (FULL)
  const size_t fixed = 75u << 20;
  short* HSP = (short*)(ws + fixed);                                // R*8192 B (packed h)

  // XQ (16384x1024 i8 = 16 MB) aliases the TOP 16 MB of fp32 d_out (64 MB).
  // OUT is written ONLY by the final gemm2 launch, after all gemm1 XQ reads
  // (stream order) — strictly read-then-overwrite; OUT re-covers all 64 MB.
  signed char* XQ = (signed char*)((char*)d_out + 50331648ull);

  // Row-chunk R for the packed int16 HSP scratch: fixed + R*8192 bytes.
  int R = 128;
  const int cands[8] = {16384, 8192, 4096, 2048, 1024, 512, 256, 128};
  for (int i = 0; i < 8; ++i) {
    if (fixed + (size_t)cands[i] * 8192ull <= ws_size) { R = cands[i]; break; }
  }

  hipLaunchKernelGGL(k_init, dim3(64), dim3(256), 0, stream, ROWMAX, SUMS);
  hipLaunchKernelGGL(k_absmean2, dim3(4096), dim3(256), 0, stream, W1, W2, SUMS);
  hipLaunchKernelGGL(k_quantw2, dim3(4096), dim3(256), 0, stream, W1, W2, W1Q, W2Q, SUMS);
  hipLaunchKernelGGL(k_quantx, dim3(16384), dim3(256), 0, stream, X, XQ, DQX);

  const int nchunk = 16384 / R;
  for (int c = 0; c < nchunk; ++c) {
    const int row0 = c * R;
    hipLaunchKernelGGL(k_gemm1, dim3(R / 128, 32), dim3(256), 0, stream,
                       XQ + (size_t)row0 * 1024, W1Q, DQX + row0, SUMS,
                       HSP, MBLK + (size_t)row0 * 32, ROWMAX + row0);
    hipLaunchKernelGGL(k_quanth, dim3(R / 4), dim3(256), 0, stream,
                       HSP, MBLK + (size_t)row0 * 32, ROWMAX + row0,
                       HQ + (size_t)row0 * 4096);
  }
  // Single full-size GEMM2: grid (128,8) = 1024 wgs, 3 blocks/CU target.
  hipLaunchKernelGGL(k_gemm2, dim3(128, 8), dim3(256), 0, stream,
                     HQ, W2Q, ROWMAX, SUMS + 1, OUT);
}

// Round 6
// 408.044 us; speedup vs baseline: 1.0492x; 1.0492x over previous
//
#include <hip/hip_runtime.h>
#include <hip/hip_bf16.h>
#include <cstdint>
#include <cmath>

// ---------------- types / helpers ----------------
typedef int intx4 __attribute__((ext_vector_type(4)));

#define EPSQ 1e-5f

// async global->LDS, 16B per lane. LDS dest = wave-uniform base + lane*16.
__device__ __forceinline__ void async16(const void* g, void* l) {
  __builtin_amdgcn_global_load_lds(
      (const __attribute__((address_space(1))) unsigned int*)(uintptr_t)g,
      (__attribute__((address_space(3))) unsigned int*)(unsigned int)(uintptr_t)l,
      16, 0, 0);
}

__device__ __forceinline__ int q8(float v, float scale, float lo, float hi) {
  return (int)fminf(fmaxf(rintf(v * scale), lo), hi);
}

// packed snorm16 quant: D = {rne(clamp(a,-1,1)*32767), rne(clamp(b,-1,1)*32767)}
__device__ __forceinline__ unsigned int pknorm_i16(float a, float b) {
  unsigned int r;
  asm("v_cvt_pknorm_i16_f32 %0, %1, %2" : "=v"(r) : "v"(a), "v"(b));
  return r;
}

// Branchless exact-GELU via Abramowitz-Stegun 7.1.26 rational erf.
__device__ __forceinline__ float fast_gelu(float y) {
  const float t = y * 0.70710678118654752f;
  const float x = fabsf(t);
  const float u = __builtin_amdgcn_rcpf(__builtin_fmaf(0.3275911f, x, 1.0f));
  float p = __builtin_fmaf(1.061405429f, u, -1.453152027f);
  p = __builtin_fmaf(p, u, 1.421413741f);
  p = __builtin_fmaf(p, u, -0.284496736f);
  p = __builtin_fmaf(p, u, 0.254829592f);
  p = p * u;
  const float e = __expf(-x * x);
  const float erf_abs = __builtin_fmaf(-p, e, 1.0f);
  const float erf_t = copysignf(erf_abs, t);
  return 0.5f * y * (1.0f + erf_t);
}

// ---------------- init ----------------
__global__ void k_init(float* rowmax, double* sums) {
  int i = blockIdx.x * 256 + threadIdx.x;
  if (i < 16384) rowmax[i] = 0.0f;
  if (i < 2) sums[i] = 0.0;
}

// ---------------- abs-sum of 2x 4194304 fp32 (-> fp64 acc), both weights ----------
__global__ __launch_bounds__(256) void k_absmean2(const float* __restrict__ W1,
                                                  const float* __restrict__ W2,
                                                  double* __restrict__ sums) {
  __shared__ double wsum[4];
  const int tid = threadIdx.x;
  const int which = blockIdx.x >> 11;                 // 0: W1, 1: W2
  const float* __restrict__ W = which ? W2 : W1;
  const size_t base = ((size_t)(blockIdx.x & 2047) * 256 + tid) * 8;
  float4 a = *(const float4*)(W + base);
  float4 b = *(const float4*)(W + base + 4);
  float s = fabsf(a.x) + fabsf(a.y) + fabsf(a.z) + fabsf(a.w) +
            fabsf(b.x) + fabsf(b.y) + fabsf(b.z) + fabsf(b.w);
  double d = (double)s;
#pragma unroll
  for (int i = 1; i < 64; i <<= 1) d += __shfl_xor(d, i);
  const int lane = tid & 63, wave = tid >> 6;
  if (lane == 0) wsum[wave] = d;
  __syncthreads();
  if (tid == 0) atomicAdd(sums + which, wsum[0] + wsum[1] + wsum[2] + wsum[3]);
}

// ---------------- ternary weight quant (fp32 in) -> int8 {-1,0,1}, both weights ----
__global__ __launch_bounds__(256) void k_quantw2(const float* __restrict__ W1,
                                                 const float* __restrict__ W2,
                                                 signed char* __restrict__ W1Q,
                                                 signed char* __restrict__ W2Q,
                                                 const double* __restrict__ sums) {
  const int which = blockIdx.x >> 11;
  const float* __restrict__ W = which ? W2 : W1;
  signed char* __restrict__ WQ = which ? W2Q : W1Q;
  const float s = fmaxf((float)(sums[which] * (1.0 / 4194304.0)), EPSQ);
  const float inv_s = 1.0f / s;
  const size_t base = ((size_t)(blockIdx.x & 2047) * 256 + threadIdx.x) * 8;
  float4 a = *(const float4*)(W + base);
  float4 b = *(const float4*)(W + base + 4);
  float v[8] = {a.x, a.y, a.z, a.w, b.x, b.y, b.z, b.w};
  unsigned int lo = 0, hi = 0;
#pragma unroll
  for (int j = 0; j < 4; ++j) {
    lo |= ((unsigned int)(q8(v[j], inv_s, -1.f, 1.f) & 0xff)) << (8 * j);
    hi |= ((unsigned int)(q8(v[4 + j], inv_s, -1.f, 1.f) & 0xff)) << (8 * j);
  }
  uint2 o; o.x = lo; o.y = hi;
  *(uint2*)(WQ + base) = o;
}

// ---------------- per-token int8 act quant of x (fp32 in, 1024/row) ----------------
__global__ __launch_bounds__(256) void k_quantx(const float* __restrict__ X,
                                                signed char* __restrict__ XQ,
                                                float* __restrict__ dqx) {
  __shared__ float wmax[4];
  const int row = blockIdx.x, tid = threadIdx.x;
  const size_t base = (size_t)row * 1024 + tid * 4;
  float4 a = *(const float4*)(X + base);
  float m = fmaxf(fmaxf(fabsf(a.x), fabsf(a.y)), fmaxf(fabsf(a.z), fabsf(a.w)));
#pragma unroll
  for (int i = 1; i < 64; i <<= 1) m = fmaxf(m, __shfl_xor(m, i));
  const int lane = tid & 63, wave = tid >> 6;
  if (lane == 0) wmax[wave] = m;
  __syncthreads();
  m = fmaxf(fmaxf(wmax[0], wmax[1]), fmaxf(wmax[2], wmax[3]));
  m = fmaxf(m, EPSQ);
  const float scale = 127.f / m;
  if (tid == 0) dqx[row] = m * (1.f / 127.f);
  unsigned int p = ((unsigned int)(q8(a.x, scale, -128.f, 127.f) & 0xff)) |
                   ((unsigned int)(q8(a.y, scale, -128.f, 127.f) & 0xff) << 8) |
                   ((unsigned int)(q8(a.z, scale, -128.f, 127.f) & 0xff) << 16) |
                   ((unsigned int)(q8(a.w, scale, -128.f, 127.f) & 0xff) << 24);
  *(unsigned int*)(XQ + base) = p;
}

// ---------------- 256x256 8-phase-style pipelined GEMM mainloop (m201 port) --------
// C[256x256] = A[256xK] * B[256xK]^T, int8 -> int32 exact (mfma_i32_16x16x64_i8).
// 512 threads = 8 waves (2M x 4N); per-wave 128x64 out = 8x4 frags.
// K-step = 128 B; LDS = 2 buffers x (A 32KB + B 32KB) = 128 KB.
// Per K-step: 4 phases. Phase p: {ds_read A-quadrant mi={2p,2p+1} (4 b128; phase 0
// also reads all B frags, 8 b128, kept in regs) | issue stage rounds for step t+1
// into buf^1 ({3,3,2,0} of 8 rounds) | s_barrier | setprio(1) 16 MFMA setprio(0)
// | s_barrier}. Step boundary: vmcnt(0) sits >=1 full MFMA phase after the last
// stage issue (phase 2) -> near-free drain; all waves then barrier before reading
// buf^1 (cross-wave staging visibility).
// Buffer-reuse ledger: step t reads buf(t&1), stages t+1 into buf^1. Step t+1
// stages t+2 into buf(t&1): issued after step t's trailing barrier, by which
// every wave's step-t ds_reads completed (lgkmcnt before MFMA, MFMA before
// barrier) -> no overwrite hazard.
// Swizzle (both-sides, rule 21): granule g_phys = g_log ^ (row&7), applied to the
// per-lane GLOBAL source address (LDS dest stays linear) and to the ds_read
// offset. Wave read pattern: 16 lanes share granule-XOR spread over 8 row
// parities -> <=2-way bank conflict (free); lanes lc,lc+8 alias 1024B apart.
template <int KB>
__device__ __forceinline__ void gemm_mainloop256(const signed char* __restrict__ A,
                                                 const signed char* __restrict__ B,
                                                 int bm, int bn, int tid, char* lds,
                                                 intx4 (&acc)[8][4]) {
  const int wave = tid >> 6, lane = tid & 63;
  const int wm = wave >> 2, wn = wave & 3;
  const int kq = lane >> 4, lc = lane & 15;
  constexpr int NS = KB / 128;  // K-steps

  // staging: 8 rounds/step; round j covers rows [j&3)*64 .. ) of A (j<4) or B.
  const int rr = tid >> 3;
  const int gs16 = (((tid & 7) ^ (rr & 7)) << 4);  // pre-swizzled granule*16
  unsigned int goff[8];
#pragma unroll
  for (int j = 0; j < 8; ++j) {
    const int rowbase = ((j < 4) ? bm : bn) * 256 + (j & 3) * 64 + rr;
    goff[j] = (unsigned int)rowbase * (unsigned int)KB + gs16;
  }

  // fragment ds_read bases (ks=0); ks=1 = base ^ 64 (granule bit2 flip).
  const int fsw = ((kq ^ (lc & 7)) << 4);
  const int abase = (wm * 128 + lc) * 128 + fsw;
  const int bbase = 32768 + (wn * 64 + lc) * 128 + fsw;

#pragma unroll
  for (int mi = 0; mi < 8; ++mi)
#pragma unroll
    for (int ni = 0; ni < 4; ++ni) {
      intx4 z = {0, 0, 0, 0};
      acc[mi][ni] = z;
    }

  // prologue: stage step 0 into buf0
#pragma unroll
  for (int j = 0; j < 8; ++j)
    async16(((j < 4) ? A : B) + (size_t)goff[j],
            lds + j * 8192 + wave * 1024);
  asm volatile("s_waitcnt vmcnt(0)" ::: "memory");
  __builtin_amdgcn_s_barrier();
  __builtin_amdgcn_sched_barrier(0);

  for (int t = 0; t < NS; ++t) {
    char* buf = lds + ((t & 1) << 16);
    char* nbuf = lds + (((t + 1) & 1) << 16);
    const size_t k0n = (size_t)(t + 1) * 128;
    const bool more = (t + 1 < NS);
    intx4 bf[4][2];
#pragma unroll
    for (int p = 0; p < 4; ++p) {
      // ds-load this phase's A quadrant (and all B in phase 0)
      intx4 af[2][2];
#pragma unroll
      for (int h = 0; h < 2; ++h) {
        const int o = abase + (2 * p + h) * 2048;
        af[h][0] = *(const intx4*)(buf + o);
        af[h][1] = *(const intx4*)(buf + (o ^ 64));
      }
      if (p == 0) {
#pragma unroll
        for (int ni = 0; ni < 4; ++ni) {
          const int o = bbase + ni * 2048;
          bf[ni][0] = *(const intx4*)(buf + o);
          bf[ni][1] = *(const intx4*)(buf + (o ^ 64));
        }
      }
      // stage rounds for step t+1: {3,3,2,0} across phases
      if (more) {
        if (p == 0) {
          async16(A + (size_t)goff[0] + k0n, nbuf + 0 * 8192 + wave * 1024);
          async16(A + (size_t)goff[1] + k0n, nbuf + 1 * 8192 + wave * 1024);
          async16(A + (size_t)goff[2] + k0n, nbuf + 2 * 8192 + wave * 1024);
        } else if (p == 1) {
          async16(A + (size_t)goff[3] + k0n, nbuf + 3 * 8192 + wave * 1024);
          async16(B + (size_t)goff[4] + k0n, nbuf + 4 * 8192 + wave * 1024);
          async16(B + (size_t)goff[5] + k0n, nbuf + 5 * 8192 + wave * 1024);
        } else if (p == 2) {
          async16(B + (size_t)goff[6] + k0n, nbuf + 6 * 8192 + wave * 1024);
          async16(B + (size_t)goff[7] + k0n, nbuf + 7 * 8192 + wave * 1024);
        }
      }
      __builtin_amdgcn_s_barrier();
      __builtin_amdgcn_sched_barrier(0);
      __builtin_amdgcn_s_setprio(1);
#pragma unroll
      for (int ks = 0; ks < 2; ++ks)
#pragma unroll
        for (int h = 0; h < 2; ++h)
#pragma unroll
          for (int ni = 0; ni < 4; ++ni)
            acc[2 * p + h][ni] = __builtin_amdgcn_mfma_i32_16x16x64_i8(
                af[h][ks], bf[ni][ks], acc[2 * p + h][ni], 0, 0, 0);
      __builtin_amdgcn_s_setprio(0);
      __builtin_amdgcn_sched_barrier(0);
      if (p == 3 && more) asm volatile("s_waitcnt vmcnt(0)" ::: "memory");
      __builtin_amdgcn_s_barrier();
    }
  }
}

// ---------------- GEMM1 + dequant + exact GELU + packed int16 h store --------------
__global__ __launch_bounds__(512, 2) void k_gemm1(const signed char* __restrict__ A,
                                                  const signed char* __restrict__ B,
                                                  const float* __restrict__ dqx,
                                                  const double* __restrict__ sums,
                                                  short* __restrict__ HSP,
                                                  float* __restrict__ mblk,
                                                  float* __restrict__ rowmax) {
  __shared__ __attribute__((aligned(16))) char lds[131072];
  const int tid = threadIdx.x;
  // bijective XCD swizzle (grid multiple of 8), bn-fastest within an XCD slab:
  // each XCD keeps a contiguous bm slab L2-hot while sweeping weight columns.
  const int q = gridDim.x >> 3;
  const int fid = blockIdx.x;
  const int swz = (fid & 7) * q + (fid >> 3);
  const int bm = swz >> 4, bn = swz & 15;

  intx4 acc[8][4];
  gemm_mainloop256<1024>(A, B, bm, bn, tid, lds, acc);

  const int wave = tid >> 6, lane = tid & 63;
  const int wm = wave >> 2, wn = wave & 3;
  const int kq = lane >> 4, lc = lane & 15;
  const float s1 = fmaxf((float)(sums[0] * (1.0 / 4194304.0)), EPSQ);

  __syncthreads();               // mainloop done; reuse ring LDS for smax
  float* smax = (float*)lds;
  if (tid < 256) smax[tid] = 0.0f;
  __syncthreads();

  // pass 1: dequant + GELU, stash h bits into acc; per-row block max via
  // 16-lane shuffle reduce, one atomic per lane-group.
#pragma unroll
  for (int mi = 0; mi < 8; ++mi) {
#pragma unroll
    for (int r = 0; r < 4; ++r) {
      const int lrow = wm * 128 + mi * 16 + kq * 4 + r;
      const int crow = bm * 256 + lrow;  // chunk-local row
      const float f = s1 * dqx[crow];
      float mx = 0.f;
#pragma unroll
      for (int ni = 0; ni < 4; ++ni) {
        float y = (float)acc[mi][ni][r] * f;
        float h = fast_gelu(y);
        acc[mi][ni][r] = (int)__float_as_uint(h);
        mx = fmaxf(mx, fabsf(h));
      }
#pragma unroll
      for (int s = 1; s < 16; s <<= 1) mx = fmaxf(mx, __shfl_xor(mx, s));
      if (lc == 0) atomicMax((unsigned int*)&smax[lrow], __float_as_uint(mx));
    }
  }
  __syncthreads();
  if (tid < 256) {
    mblk[(size_t)(bm * 256 + tid) * 16 + bn] = smax[tid];
    atomicMax((unsigned int*)&rowmax[bm * 256 + tid], __float_as_uint(smax[tid]));
  }

  // pass 2: packed snorm16 quad-row store (acc[mi][ni][0..3] = 4 consecutive
  // rows, same column -> 2x pknorm + 1 uint2 store).
#pragma unroll
  for (int mi = 0; mi < 8; ++mi) {
    const int lrow0 = wm * 128 + mi * 16 + kq * 4;
    const int qr = (bm * 256 + lrow0) >> 2;  // chunk-local quad-row
    float inv[4];
#pragma unroll
    for (int r = 0; r < 4; ++r)
      inv[r] = __builtin_amdgcn_rcpf(fmaxf(smax[lrow0 + r], 1e-30f));
#pragma unroll
    for (int ni = 0; ni < 4; ++ni) {
      const int gcol = bn * 256 + wn * 64 + ni * 16 + lc;
      const float h0 = __uint_as_float((unsigned int)acc[mi][ni][0]) * inv[0];
      const float h1 = __uint_as_float((unsigned int)acc[mi][ni][1]) * inv[1];
      const float h2 = __uint_as_float((unsigned int)acc[mi][ni][2]) * inv[2];
      const float h3 = __uint_as_float((unsigned int)acc[mi][ni][3]) * inv[3];
      uint2 o;
      o.x = pknorm_i16(h0, h1);
      o.y = pknorm_i16(h2, h3);
      *(uint2*)(HSP + ((size_t)qr * 4096 + gcol) * 4) = o;
    }
  }
}

// ---------------- requantize h: packed int16 (block scale) -> int8 (row scale) -----
__global__ __launch_bounds__(256) void k_quanth(const short* __restrict__ HSP,
                                                const float* __restrict__ mblk,
                                                const float* __restrict__ rowmax,
                                                signed char* __restrict__ HQ) {
  const int gid = blockIdx.x * 256 + threadIdx.x;
  const int qr = gid >> 8;            // chunk-local quad-row
  const int cg = gid & 255;           // 16-col group
  const int c0 = cg * 16;
  const int blk = c0 >> 8;            // 256-col block
  const int row0 = qr * 4;            // chunk-local row
  float fb[4];
#pragma unroll
  for (int r = 0; r < 4; ++r) {
    const float m = fmaxf(rowmax[row0 + r], EPSQ);
    fb[r] = mblk[(size_t)(row0 + r) * 16 + blk] * (127.0f / 32767.0f) / m;
  }
  const uint4* src = (const uint4*)(HSP + ((size_t)qr * 4096 + c0) * 4);
  uint4 L[8];
#pragma unroll
  for (int j = 0; j < 8; ++j) L[j] = src[j];

  unsigned int out[4][4] = {};
#pragma unroll
  for (int j = 0; j < 16; ++j) {
    const unsigned int u01 = (j & 1) ? L[j >> 1].z : L[j >> 1].x;
    const unsigned int u23 = (j & 1) ? L[j >> 1].w : L[j >> 1].y;
    const float s0 = (float)(short)(u01 & 0xffff);
    const float s1 = (float)(short)(u01 >> 16);
    const float s2 = (float)(short)(u23 & 0xffff);
    const float s3 = (float)(short)(u23 >> 16);
    out[0][j >> 2] |= ((unsigned int)(q8(s0, fb[0], -128.f, 127.f) & 0xff)) << (8 * (j & 3));
    out[1][j >> 2] |= ((unsigned int)(q8(s1, fb[1], -128.f, 127.f) & 0xff)) << (8 * (j & 3));
    out[2][j >> 2] |= ((unsigned int)(q8(s2, fb[2], -128.f, 127.f) & 0xff)) << (8 * (j & 3));
    out[3][j >> 2] |= ((unsigned int)(q8(s3, fb[3], -128.f, 127.f) & 0xff)) << (8 * (j & 3));
  }
#pragma unroll
  for (int r = 0; r < 4; ++r) {
    uint4 o; o.x = out[r][0]; o.y = out[r][1]; o.z = out[r][2]; o.w = out[r][3];
    *(uint4*)(HQ + (size_t)(row0 + r) * 4096 + c0) = o;
  }
}

// ---------------- GEMM2 + dequant -> fp32 out (global rows, single launch) ----------
__global__ __launch_bounds__(512, 2) void k_gemm2(const signed char* __restrict__ A,
                                                  const signed char* __restrict__ B,
                                                  const float* __restrict__ rowmax,
                                                  const double* __restrict__ sums,
                                                  float* __restrict__ OUT) {
  __shared__ __attribute__((aligned(16))) char lds[131072];
  const int tid = threadIdx.x;
  const int q = gridDim.x >> 3;
  const int fid = blockIdx.x;
  const int swz = (fid & 7) * q + (fid >> 3);
  const int bm = swz >> 2, bn = swz & 3;

  intx4 acc[8][4];
  gemm_mainloop256<4096>(A, B, bm, bn, tid, lds, acc);

  const int wave = tid >> 6, lane = tid & 63;
  const int wm = wave >> 2, wn = wave & 3;
  const int kq = lane >> 4, lc = lane & 15;
  const float s2 = fmaxf((float)(sums[0] * (1.0 / 4194304.0)), EPSQ);
#pragma unroll
  for (int mi = 0; mi < 8; ++mi) {
#pragma unroll
    for (int r = 0; r < 4; ++r) {
      const int crow = bm * 256 + wm * 128 + mi * 16 + kq * 4 + r;
      const float dqh = fmaxf(rowmax[crow], EPSQ) * (1.f / 127.f);
      const float f = s2 * dqh;
#pragma unroll
      for (int ni = 0; ni < 4; ++ni) {
        const int gcol = bn * 256 + wn * 64 + ni * 16 + lc;
        OUT[(size_t)crow * 1024 + gcol] = (float)acc[mi][ni][r] * f;
      }
    }
  }
}

// ---------------- launcher ----------------
extern "C" void kernel_launch(void* const* d_in, const int* in_sizes, int n_in,
                              void* d_out, int out_size, void* d_ws, size_t ws_size,
                              hipStream_t stream) {
  const float* X  = (const float*)d_in[0];  // [16384][1024] fp32
  const float* W1 = (const float*)d_in[1];  // [4096][1024]  fp32
  const float* W2 = (const float*)d_in[2];  // [1024][4096]  fp32
  float* OUT = (float*)d_out;               // [16384][1024] fp32 (64 MB)

  char* ws = (char*)d_ws;
  // Fixed-footprint region: 10 MB misc + 64 MB full HQ = 74 MB
  signed char* W1Q = (signed char*)(ws);                            // 4 MB
  signed char* W2Q = (signed char*)(ws + (4u << 20));               // 4 MB
  float* DQX       = (float*)(ws + (8u << 20));                     // 64 KB
  float* ROWMAX    = (float*)(ws + (8u << 20) + 65536);             // 64 KB
  double* SUMS     = (double*)(ws + (8u << 20) + 131072);           // 16 B
  float* MBLK      = (float*)(ws + (9u << 20));                     // 1 MB [16384][16]
  signed char* HQ  = (signed char*)(ws + (10u << 20));              // 64 MB (FULL)
  const size_t fixed = 74u << 20;
  short* HSP = (short*)(ws + fixed);                                // R*8192 B (packed h)

  // XQ (16384x1024 i8 = 16 MB) aliases the TOP 16 MB of fp32 d_out (64 MB).
  // OUT is written ONLY by the final gemm2 launch, after all gemm1 XQ reads
  // (stream order) — strictly read-then-overwrite; OUT re-covers all 64 MB.
  signed char* XQ = (signed char*)((char*)d_out + 50331648ull);

  // Row-chunk R (multiple of 256) for the packed int16 HSP scratch.
  int R = 256;
  const int cands[7] = {16384, 8192, 4096, 2048, 1024, 512, 256};
  for (int i = 0; i < 7; ++i) {
    if (fixed + (size_t)cands[i] * 8192ull <= ws_size) { R = cands[i]; break; }
  }

  hipLaunchKernelGGL(k_init, dim3(64), dim3(256), 0, stream, ROWMAX, SUMS);
  hipLaunchKernelGGL(k_absmean2, dim3(4096), dim3(256), 0, stream, W1, W2, SUMS);
  hipLaunchKernelGGL(k_quantw2, dim3(4096), dim3(256), 0, stream, W1, W2, W1Q, W2Q, SUMS);
  hipLaunchKernelGGL(k_quantx, dim3(16384), dim3(256), 0, stream, X, XQ, DQX);

  const int nchunk = 16384 / R;
  for (int c = 0; c < nchunk; ++c) {
    const int row0 = c * R;
    hipLaunchKernelGGL(k_gemm1, dim3((R / 256) * 16), dim3(512), 0, stream,
                       XQ + (size_t)row0 * 1024, W1Q, DQX + row0, SUMS,
                       HSP, MBLK + (size_t)row0 * 16, ROWMAX + row0);
    hipLaunchKernelGGL(k_quanth, dim3(R / 4), dim3(256), 0, stream,
                       HSP, MBLK + (size_t)row0 * 16, ROWMAX + row0,
                       HQ + (size_t)row0 * 4096);
  }
  // Single full-size GEMM2: grid 256 wgs (1 block/CU at 128 KB LDS).
  hipLaunchKernelGGL(k_gemm2, dim3(256), dim3(512), 0, stream,
                     HQ, W2Q, ROWMAX, SUMS + 1, OUT);
}